// Round 11
// baseline (507.052 us; speedup 1.0000x reference)
//
#include <hip/hip_runtime.h>
#include <hip/hip_bf16.h>
#include <cstdint>

#define N_NOTES 4096
#define SIZE 64
#define NE 14
#define NITER 5
#define MAXDEG 64
#define ASTR 968   /* padded LDS k-stride (ushorts) */
#define HPAD 4113  /* h rows incl. zero pad rows 4096..4112 (dummy idx 0x1010=4112) */
#define PWN 184320 /* 3*4*30*512 fragment-packed Wt elements */
#define PUN 4096   /* 4*2*512 fragment-packed Ut elements */
#define PSTR 264   /* PS slot stride in f32 */
#define NBLK 256   /* persistent grid = #CUs; 16 waves @ >64 VGPR -> exactly 1 block/CU */

typedef __attribute__((ext_vector_type(8))) short short8;
typedef __attribute__((ext_vector_type(4))) float float4v;

__device__ __forceinline__ ushort f2bf(float f){
  union{float f; uint32_t u;} x; x.f=f;
  uint32_t r = x.u + 0x7fffu + ((x.u>>16)&1u);
  return (ushort)(r>>16);
}
__device__ __forceinline__ float bf2f(ushort h){
  union{uint32_t u; float f;} x; x.u=((uint32_t)h)<<16; return x.f;
}
__device__ __forceinline__ void split_bf(float v, ushort& hi, ushort& lo){
  hi = f2bf(v);
  lo = f2bf(v - bf2f(hi));   // hi+lo ~ 16-17 mantissa bits
}

// ---- Setup: deg zero, adj dummy-fill, weight pack, h0 init, barrier zero
__global__ __launch_bounds__(256) void k_setup(int* __restrict__ deg, uint32_t* __restrict__ adj32,
                                               const float* __restrict__ wz, const float* __restrict__ wr,
                                               const float* __restrict__ wh, const float* __restrict__ uz,
                                               const float* __restrict__ ur, const float* __restrict__ uh,
                                               ushort* __restrict__ PWH, ushort* __restrict__ PWL,
                                               ushort* __restrict__ PUH, ushort* __restrict__ PUL,
                                               const float4v* __restrict__ x4, float4v* __restrict__ h04,
                                               float* __restrict__ h0pad, float* __restrict__ h1pad,
                                               int* __restrict__ bar){
  int i = blockIdx.x*256 + threadIdx.x;          // 0..524287
  if (i == 0) bar[0] = 0;
  if (i < NE*N_NOTES) deg[i] = 0;
  for (int j = i; j < NE*N_NOTES*MAXDEG/2; j += 2048*256)
    adj32[j] = 0x10101010u;                      // two ushorts of 4112 (dummy -> zero row)
  if (i < PWN){
    int j = i & 7, lane = (i>>3)&63, t = i>>9;   // t = (g*4+cb)*30+kk
    int kk = t % 30, wg = t/30; int cb = wg & 3, g = wg >> 2;
    int col = g*64 + cb*16 + (lane&15);
    int k = kk*32 + ((lane>>4)<<3) + j;
    int e = k >> 6, d = k & 63, f = col & 63;
    float v;
    if (e < NE){
      const float* wp = (g==0)?wz:(g==1)?wr:wh;
      v = wp[(e*64 + d)*64 + f];
    } else {
      v = (g==0) ? uz[d*64+f] : (g==1) ? ur[d*64+f] : 0.0f;
    }
    ushort hi,lo; split_bf(v,hi,lo);
    PWH[i]=hi; PWL[i]=lo;
  } else if (i < PWN + PUN){
    int i2 = i - PWN;
    int j = i2 & 7, lane = (i2>>3)&63, t = i2>>9; // t = cb*2+kk
    int kk = t & 1, cb = t >> 1;
    int col = cb*16 + (lane&15);
    int k = kk*32 + ((lane>>4)<<3) + j;
    float v = uh[k*64 + col];
    ushort hi,lo; split_bf(v,hi,lo);
    PUH[i2]=hi; PUL[i2]=lo;
  }
  if (i < N_NOTES*SIZE/4) h04[i] = x4[i];        // h0 = x
  if (i < (HPAD-N_NOTES)*SIZE){ h0pad[i] = 0.f; h1pad[i] = 0.f; }
}

// ---- Pass 1: edge_matrix [14,4096,4096] f32 -> per-(e,n) adjacency (column lists)
__global__ __launch_bounds__(256) void k_build(const float4v* __restrict__ edge4,
                                               int* __restrict__ deg,
                                               ushort* __restrict__ adj){
  int row = blockIdx.x;            // e*4096 + m
  int e = row >> 12, m = row & 4095;
  const float4v* p = edge4 + (size_t)row * (N_NOTES/4);
  int t = threadIdx.x;
  #pragma unroll
  for (int i=0;i<4;i++){
    int idx4 = t + i*256;
    float4v v = p[idx4];
    int nbase = idx4*4;
    #pragma unroll
    for (int j=0;j<4;j++){
      if (v[j] != 0.0f){
        int n = nbase + j;
        int slot = atomicAdd(&deg[(e<<12)+n], 1);
        if (slot < MAXDEG) adj[(size_t)((e<<12)+n)*MAXDEG + slot] = (ushort)m;
      }
    }
  }
}

// ---- Persistent fused kernel: all 5 iterations, software grid barrier between them.
//      Body per iteration is the proven r6 lockstep structure (16 rows, 16 waves,
//      gather -> split-K GEMM1 -> PS reduce + gates -> GEMM2 -> blend).
__global__ __launch_bounds__(1024, 4)
void k_mega(const int* __restrict__ deg, const ushort* __restrict__ adj,
            const ushort* __restrict__ PWH, const ushort* __restrict__ PWL,
            const ushort* __restrict__ PUH, const ushort* __restrict__ PUL,
            const float* __restrict__ bz, const float* __restrict__ br,
            const float* __restrict__ bh,
            float* __restrict__ h0, float* __restrict__ h1,
            float* __restrict__ out, int* __restrict__ bar){
  __shared__ ushort sh[31744];                 // 63488 B
  ushort* aHs = sh;                            // [16][ASTR]
  ushort* aLs = sh + 16*ASTR;
  float*  PSf = (float*)sh;                    // 48 slots * PSTR f32, aliases A post-MFMA
  ushort* rhH = sh + 25344;                    // 16*72
  ushort* rhL = sh + 26496;
  float*  zSf = (float*)(sh + 27648);          // 1024 f32
  float*  rSf = (float*)(sh + 29696);          // 1024 f32

  const int tid  = threadIdx.x;
  const int w    = tid >> 6;                   // wave 0..15
  const int lane = tid & 63;
  const int qi   = lane >> 4;
  const int ql   = lane & 15;
  const int l15  = lane & 15;
  const int koff = (lane >> 4) * 8;
  const int cb   = w & 3, kq = w >> 2;
  const int r0   = blockIdx.x * 16;
  const int Q    = w*4 + qi;                   // quarter id 0..63

  // ---------- adjacency state loaded ONCE, reused across all 5 iterations ----------
  int dgv[4], mvv[4];
  #pragma unroll
  for (int p=0;p<4;p++){
    int u = p*64 + Q;
    dgv[p]=0; mvv[p]=0;
    if (u < 240){
      int e = u >> 4;
      if (e < NE){
        int base = (e<<12) + r0 + (u & 15);
        int d = deg[base]; if (d > MAXDEG) d = MAXDEG;
        dgv[p] = d;
        mvv[p] = adj[(size_t)base*MAXDEG + ql];  // slots >= deg hold dummy 4112 -> zero row
      }
    }
  }

  #pragma unroll 1
  for (int it = 0; it < NITER; ++it){
    const float* hin  = (it & 1) ? h1 : h0;
    float*       hout = (it & 1) ? h0 : h1;
    const float4v* hin4 = (const float4v*)hin;

    // ---------- Phase 0: gather act tile [16][960] ----------
    #pragma unroll
    for (int p=0;p<4;p++){
      int u = p*64 + Q;
      if (u >= 240) continue;
      int e = u >> 4, ri = u & 15, n = r0 + ri;
      float4v a0={0.f,0.f,0.f,0.f}, a1=a0, a2=a0, a3=a0;
      if (e < NE){
        int mv = mvv[p];
        #pragma unroll
        for (int k=0;k<16;k+=4){
          int m0 = __shfl(mv, qi*16 + k);
          int m1 = __shfl(mv, qi*16 + k+1);
          int m2 = __shfl(mv, qi*16 + k+2);
          int m3 = __shfl(mv, qi*16 + k+3);
          a0 += hin4[m0*16 + ql];
          a1 += hin4[m1*16 + ql];
          a2 += hin4[m2*16 + ql];
          a3 += hin4[m3*16 + ql];
        }
        int dg = dgv[p];
        if (dg > 16){                            // rare tail (~0.4% of units)
          size_t base = (size_t)((e<<12)+n)*MAXDEG;
          for (int k=16;k<dg;k++){
            int m = adj[base + k];
            a0 += hin4[m*16 + ql];
          }
        }
      } else {
        a0 = hin4[n*16 + ql];                    // slot 14 = h itself
      }
      float4v acc = (a0 + a1) + (a2 + a3);
      ushort h0_,h1_,h2_,h3_,l0_,l1_,l2_,l3_;
      split_bf(acc[0],h0_,l0_); split_bf(acc[1],h1_,l1_);
      split_bf(acc[2],h2_,l2_); split_bf(acc[3],h3_,l3_);
      int o = ri*ASTR + e*64 + ql*4;
      *(ushort4*)&aHs[o] = make_ushort4(h0_,h1_,h2_,h3_);
      *(ushort4*)&aLs[o] = make_ushort4(l0_,l1_,l2_,l3_);
    }
    __syncthreads();

    // ---------- Phase 1: split-K GEMM1, wave (cb,kq), kk = kq*8 .. ----------
    float4v acc[3];
    #pragma unroll
    for (int g=0;g<3;g++) acc[g] = (float4v){0.f,0.f,0.f,0.f};
    {
      const int kk0 = kq*8;
      #pragma unroll
      for (int kx=0; kx<8; ++kx){
        const int kk = kk0 + kx;
        if (kk < 30){
          short8 aH = *(const short8*)&aHs[l15*ASTR + kk*32 + koff];
          short8 aL = *(const short8*)&aLs[l15*ASTR + kk*32 + koff];
          #pragma unroll
          for (int g=0; g<3; ++g){
            int boff = (((g*4 + cb)*30 + kk) << 9) + lane*8;
            short8 bH = *(const short8*)(PWH + boff);
            short8 bL = *(const short8*)(PWL + boff);
            acc[g] = __builtin_amdgcn_mfma_f32_16x16x32_bf16(aH,bH,acc[g],0,0,0);
            acc[g] = __builtin_amdgcn_mfma_f32_16x16x32_bf16(aH,bL,acc[g],0,0,0);
            acc[g] = __builtin_amdgcn_mfma_f32_16x16x32_bf16(aL,bH,acc[g],0,0,0);
          }
        }
      }
    }
    __syncthreads();                             // A reads done -> PS aliases A

    // ---------- publish split-K partials ----------
    {
      int crow0 = (lane>>4)*4;
      #pragma unroll
      for (int g=0;g<3;g++){
        float* slot = PSf + (size_t)(kq*12 + g*4 + cb)*PSTR;
        #pragma unroll
        for (int i=0;i<4;i++)
          slot[(crow0+i)*16 + l15] = acc[g][i];
      }
    }
    __syncthreads();

    // ---------- reduce + gates + rh ----------
    {
      int r = tid >> 6, f = tid & 63;
      int cb2 = f >> 4, c = f & 15;
      float az=0.f, ar=0.f, ah=0.f;
      #pragma unroll
      for (int k=0;k<4;k++){
        az += PSf[(size_t)(k*12 + 0 + cb2)*PSTR + r*16 + c];
        ar += PSf[(size_t)(k*12 + 4 + cb2)*PSTR + r*16 + c];
        ah += PSf[(size_t)(k*12 + 8 + cb2)*PSTR + r*16 + c];
      }
      float z  = 1.f/(1.f + expf(-(az + bz[f])));
      float rg = 1.f/(1.f + expf(-(ar + br[f])));
      float hv = hin[(size_t)(r0+r)*64 + f];
      zSf[tid] = z;
      rSf[tid] = rg;
      ushort hi,lo; split_bf(rg*hv,hi,lo);
      rhH[r*72+f] = hi;
      rhL[r*72+f] = lo;
      PSf[(size_t)(8 + cb2)*PSTR + r*16 + c] = ah;
    }
    __syncthreads();

    // ---------- waves 0..3: GEMM2 + blend + write ----------
    if (w < 4){
      const int colf = w*16 + l15;
      float4v acc2 = {0.f,0.f,0.f,0.f};
      #pragma unroll
      for (int kk=0; kk<2; ++kk){
        short8 aH = *(const short8*)&rhH[l15*72 + kk*32 + koff];
        short8 aL = *(const short8*)&rhL[l15*72 + kk*32 + koff];
        int boff = (((w<<1) + kk) << 9) + lane*8;
        short8 bH = *(const short8*)(PUH + boff);
        short8 bL = *(const short8*)(PUL + boff);
        acc2 = __builtin_amdgcn_mfma_f32_16x16x32_bf16(aH,bH,acc2,0,0,0);
        acc2 = __builtin_amdgcn_mfma_f32_16x16x32_bf16(aH,bL,acc2,0,0,0);
        acc2 = __builtin_amdgcn_mfma_f32_16x16x32_bf16(aL,bH,acc2,0,0,0);
      }
      const int crow0 = (lane>>4)*4;
      const float bhf = bh[colf];
      #pragma unroll
      for (int i=0;i<4;i++){
        int row = crow0 + i;
        float ah = PSf[(size_t)(8 + w)*PSTR + row*16 + l15];
        float z  = zSf[row*64 + colf];
        float rg = rSf[row*64 + colf];
        float ht = tanhf(ah + acc2[i] + bhf);
        size_t idx = (size_t)(r0+row)*64 + colf;
        float hn = (1.f - z)*hin[idx] + rg*ht;
        hout[idx] = hn;
        if (it == NITER-1) out[idx] = hn;
      }
    }

    // ---------- grid barrier (not after last iteration) ----------
    if (it < NITER-1){
      __syncthreads();
      if (tid == 0){
        __threadfence();                         // release: flush stores device-wide
        atomicAdd(bar, 1);
        int target = NBLK * (it + 1);
        while (atomicAdd(bar, 0) < target) __builtin_amdgcn_s_sleep(2);
        __threadfence();                         // acquire: invalidate stale cache
      }
      __syncthreads();
    }
  }
}

extern "C" void kernel_launch(void* const* d_in, const int* in_sizes, int n_in,
                              void* d_out, int out_size, void* d_ws, size_t ws_size,
                              hipStream_t stream) {
  const float* x    = (const float*)d_in[0];
  const float* edge = (const float*)d_in[1];
  const float* wz   = (const float*)d_in[2];
  const float* wr   = (const float*)d_in[3];
  const float* wh   = (const float*)d_in[4];
  const float* uz   = (const float*)d_in[5];
  const float* ur   = (const float*)d_in[6];
  const float* uh   = (const float*)d_in[7];
  const float* bz   = (const float*)d_in[8];
  const float* br   = (const float*)d_in[9];
  const float* bh   = (const float*)d_in[10];
  float* out = (float*)d_out;

  char* ws = (char*)d_ws;
  size_t off = 0;
  auto alloc = [&](size_t bytes)->void*{
    void* p = ws + off;
    off = (off + bytes + 255) & ~(size_t)255;
    return p;
  };
  const size_t EN = (size_t)NE * N_NOTES;            // 57344
  const size_t ND = (size_t)N_NOTES * SIZE;          // 262144
  int*    deg  = (int*)   alloc(EN * 4);
  ushort* adj  = (ushort*)alloc(EN * MAXDEG * 2);
  ushort* PWH  = (ushort*)alloc((size_t)PWN * 2);
  ushort* PWL  = (ushort*)alloc((size_t)PWN * 2);
  ushort* PUH  = (ushort*)alloc((size_t)PUN * 2);
  ushort* PUL  = (ushort*)alloc((size_t)PUN * 2);
  float*  h0   = (float*) alloc((size_t)HPAD * SIZE * 4);
  float*  h1   = (float*) alloc((size_t)HPAD * SIZE * 4);
  int*    bar  = (int*)   alloc(256);

  k_setup<<<2048, 256, 0, stream>>>(deg, (uint32_t*)adj,
                                    wz, wr, wh, uz, ur, uh,
                                    PWH, PWL, PUH, PUL,
                                    (const float4v*)x, (float4v*)h0,
                                    h0 + ND, h1 + ND, bar);
  k_build<<<NE*N_NOTES, 256, 0, stream>>>((const float4v*)edge, deg, adj);
  k_mega <<<NBLK, 1024, 0, stream>>>(deg, adj, PWH, PWL, PUH, PUL,
                                     bz, br, bh, h0, h1, out, bar);
}

// Round 12
// 285.259 us; speedup vs baseline: 1.7775x; 1.7775x over previous
//
#include <hip/hip_runtime.h>
#include <hip/hip_bf16.h>
#include <cstdint>

#define N_NOTES 4096
#define SIZE 64
#define NE 14
#define NITER 5
#define MAXDEG 64
#define ASTR 968   /* padded LDS k-stride (ushorts) */
#define HPAD 4113  /* h rows incl. zero pad rows 4096..4112 (dummy idx 0x1010=4112) */
#define PWN 196608 /* 3*4*32*512 fragment-packed Wt elements (kk 30,31 zero-padded) */
#define PUN 4096   /* 4*2*512 fragment-packed Ut elements */
#define PSTR 264   /* PS slot stride in f32 */

typedef __attribute__((ext_vector_type(8))) short short8;
typedef __attribute__((ext_vector_type(4))) float float4v;

__device__ __forceinline__ ushort f2bf(float f){
  union{float f; uint32_t u;} x; x.f=f;
  uint32_t r = x.u + 0x7fffu + ((x.u>>16)&1u);
  return (ushort)(r>>16);
}
__device__ __forceinline__ float bf2f(ushort h){
  union{uint32_t u; float f;} x; x.u=((uint32_t)h)<<16; return x.f;
}
__device__ __forceinline__ void split_bf(float v, ushort& hi, ushort& lo){
  hi = f2bf(v);
  lo = f2bf(v - bf2f(hi));   // hi+lo ~ 16-17 mantissa bits
}

// ---- Setup: deg zero, adj dummy-fill, weight pack (32-kk padded), h0 init
__global__ __launch_bounds__(256) void k_setup(int* __restrict__ deg, uint32_t* __restrict__ adj32,
                                               const float* __restrict__ wz, const float* __restrict__ wr,
                                               const float* __restrict__ wh, const float* __restrict__ uz,
                                               const float* __restrict__ ur, const float* __restrict__ uh,
                                               ushort* __restrict__ PWH, ushort* __restrict__ PWL,
                                               ushort* __restrict__ PUH, ushort* __restrict__ PUL,
                                               const float4v* __restrict__ x4, float4v* __restrict__ h04,
                                               float* __restrict__ h0pad, float* __restrict__ h1pad){
  int i = blockIdx.x*256 + threadIdx.x;          // 0..524287
  if (i < NE*N_NOTES) deg[i] = 0;
  for (int j = i; j < NE*N_NOTES*MAXDEG/2; j += 2048*256)
    adj32[j] = 0x10101010u;                      // two ushorts of 4112 (dummy -> zero row)
  if (i < PWN){
    int j = i & 7, lane = (i>>3)&63, t = i>>9;   // t = (g*4+cb)*32+kk
    int kk = t & 31, wg = t >> 5; int cb = wg & 3, g = wg >> 2;
    float v = 0.0f;
    if (kk < 30){
      int col = g*64 + cb*16 + (lane&15);
      int k = kk*32 + ((lane>>4)<<3) + j;
      int e = k >> 6, d = k & 63, f = col & 63;
      if (e < NE){
        const float* wp = (g==0)?wz:(g==1)?wr:wh;
        v = wp[(e*64 + d)*64 + f];
      } else {
        v = (g==0) ? uz[d*64+f] : (g==1) ? ur[d*64+f] : 0.0f;
      }
    }
    ushort hi,lo; split_bf(v,hi,lo);
    PWH[i]=hi; PWL[i]=lo;
  } else if (i < PWN + PUN){
    int i2 = i - PWN;
    int j = i2 & 7, lane = (i2>>3)&63, t = i2>>9; // t = cb*2+kk
    int kk = t & 1, cb = t >> 1;
    int col = cb*16 + (lane&15);
    int k = kk*32 + ((lane>>4)<<3) + j;
    float v = uh[k*64 + col];
    ushort hi,lo; split_bf(v,hi,lo);
    PUH[i2]=hi; PUL[i2]=lo;
  }
  if (i < N_NOTES*SIZE/4) h04[i] = x4[i];        // h0 = x
  if (i < (HPAD-N_NOTES)*SIZE){ h0pad[i] = 0.f; h1pad[i] = 0.f; }
}

// ---- Pass 1: edge_matrix [14,4096,4096] f32 -> per-(e,n) adjacency (column lists)
__global__ __launch_bounds__(256) void k_build(const float4v* __restrict__ edge4,
                                               int* __restrict__ deg,
                                               ushort* __restrict__ adj){
  int row = blockIdx.x;            // e*4096 + m
  int e = row >> 12, m = row & 4095;
  const float4v* p = edge4 + (size_t)row * (N_NOTES/4);
  int t = threadIdx.x;
  #pragma unroll
  for (int i=0;i<4;i++){
    int idx4 = t + i*256;
    float4v v = p[idx4];
    int nbase = idx4*4;
    #pragma unroll
    for (int j=0;j<4;j++){
      if (v[j] != 0.0f){
        int n = nbase + j;
        int slot = atomicAdd(&deg[(e<<12)+n], 1);
        if (slot < MAXDEG) adj[(size_t)((e<<12)+n)*MAXDEG + slot] = (ushort)m;
      }
    }
  }
}

// ---- Fused iteration (r6 lockstep body + micro-opts):
//      gather-act(LDS) -> split-K GEMM1 -> PS reduce + gates -> GEMM2 -> blend
__global__ __launch_bounds__(1024, 4)
void k_fused(const int* __restrict__ deg, const ushort* __restrict__ adj,
             const ushort* __restrict__ PWH, const ushort* __restrict__ PWL,
             const ushort* __restrict__ PUH, const ushort* __restrict__ PUL,
             const float* __restrict__ bz, const float* __restrict__ br,
             const float* __restrict__ bh,
             const float* __restrict__ hin, float* __restrict__ hout,
             float* __restrict__ out, int last){
  __shared__ ushort sh[31744];                 // 63488 B
  ushort* aHs = sh;                            // [16][ASTR]
  ushort* aLs = sh + 16*ASTR;
  float*  PSf = (float*)sh;                    // 48 slots * PSTR f32, aliases A post-MFMA
  ushort* rhH = sh + 25344;                    // 16*72
  ushort* rhL = sh + 26496;
  float*  zSf = (float*)(sh + 27648);          // 1024 f32
  float*  rSf = (float*)(sh + 29696);          // 1024 f32

  const int tid  = threadIdx.x;
  const int w    = tid >> 6;                   // wave 0..15
  const int lane = tid & 63;
  const int qi   = lane >> 4;
  const int ql   = lane & 15;
  const int l15  = lane & 15;
  const int koff = (lane >> 4) * 8;
  const int cb   = w & 3, kq = w >> 2;
  const int r0   = blockIdx.x * 16;
  const int Q    = w*4 + qi;                   // quarter id 0..63
  const float4v* hin4 = (const float4v*)hin;
  const int bbase = (3*0 + (w & 31)); (void)bbase;

  // ---------- adjacency prefetch (deg + lane's slot for 4 units) ----------
  int dgv[4], mvv[4];
  #pragma unroll
  for (int p=0;p<4;p++){
    int u = p*64 + Q;
    dgv[p]=0; mvv[p]=0;
    if (u < 240){
      int e = u >> 4;
      if (e < NE){
        int base = (e<<12) + r0 + (u & 15);
        int d = deg[base]; if (d > MAXDEG) d = MAXDEG;
        dgv[p] = d;
        mvv[p] = adj[(size_t)base*MAXDEG + ql];  // slots >= deg hold dummy 4112 -> zero row
      }
    }
  }

  // ---------- Phase 0: gather act tile [16][960] ----------
  #pragma unroll
  for (int p=0;p<4;p++){
    int u = p*64 + Q;
    if (u >= 240) continue;
    int e = u >> 4, ri = u & 15, n = r0 + ri;
    float4v a0={0.f,0.f,0.f,0.f}, a1=a0, a2=a0, a3=a0;
    if (e < NE){
      int mv = mvv[p];
      #pragma unroll
      for (int k=0;k<16;k+=4){
        int m0 = __shfl(mv, qi*16 + k);
        int m1 = __shfl(mv, qi*16 + k+1);
        int m2 = __shfl(mv, qi*16 + k+2);
        int m3 = __shfl(mv, qi*16 + k+3);
        a0 += hin4[m0*16 + ql];
        a1 += hin4[m1*16 + ql];
        a2 += hin4[m2*16 + ql];
        a3 += hin4[m3*16 + ql];
      }
      int dg = dgv[p];
      if (dg > 16){                            // rare tail (~0.4% of units)
        size_t base = (size_t)((e<<12)+n)*MAXDEG;
        for (int k=16;k<dg;k++){
          int m = adj[base + k];
          a0 += hin4[m*16 + ql];
        }
      }
    } else {
      a0 = hin4[n*16 + ql];                    // slot 14 = h itself
    }
    float4v acc = (a0 + a1) + (a2 + a3);
    ushort h0_,h1_,h2_,h3_,l0_,l1_,l2_,l3_;
    split_bf(acc[0],h0_,l0_); split_bf(acc[1],h1_,l1_);
    split_bf(acc[2],h2_,l2_); split_bf(acc[3],h3_,l3_);
    int o = ri*ASTR + e*64 + ql*4;
    *(ushort4*)&aHs[o] = make_ushort4(h0_,h1_,h2_,h3_);
    *(ushort4*)&aLs[o] = make_ushort4(l0_,l1_,l2_,l3_);
  }

  // ---------- prefetch first-kk B frags; loads in flight across the barrier ----------
  short8 pbH[3], pbL[3];
  {
    const int kk0 = kq*8;
    #pragma unroll
    for (int g=0; g<3; ++g){
      int boff = (((g*4 + cb) << 5) + kk0 << 9) + lane*8;
      pbH[g] = *(const short8*)(PWH + boff);
      pbL[g] = *(const short8*)(PWL + boff);
    }
  }
  __syncthreads();

  // ---------- Phase 1: split-K GEMM1, wave (cb,kq), kk = kq*8 .. kq*8+7 (B zero-padded) ----------
  float4v acc[3];
  #pragma unroll
  for (int g=0;g<3;g++) acc[g] = (float4v){0.f,0.f,0.f,0.f};
  {
    const int kk0 = kq*8;
    #pragma unroll
    for (int kx=0; kx<8; ++kx){
      const int kk  = kk0 + kx;
      const int kka = kk < 30 ? kk : 29;       // clamp A offset in-bounds; B is zero there
      short8 aH = *(const short8*)&aHs[l15*ASTR + kka*32 + koff];
      short8 aL = *(const short8*)&aLs[l15*ASTR + kka*32 + koff];
      #pragma unroll
      for (int g=0; g<3; ++g){
        short8 bH, bL;
        if (kx == 0){ bH = pbH[g]; bL = pbL[g]; }
        else {
          int boff = ((((g*4 + cb) << 5) + kk) << 9) + lane*8;
          bH = *(const short8*)(PWH + boff);
          bL = *(const short8*)(PWL + boff);
        }
        acc[g] = __builtin_amdgcn_mfma_f32_16x16x32_bf16(aH,bH,acc[g],0,0,0);
        acc[g] = __builtin_amdgcn_mfma_f32_16x16x32_bf16(aH,bL,acc[g],0,0,0);
        acc[g] = __builtin_amdgcn_mfma_f32_16x16x32_bf16(aL,bH,acc[g],0,0,0);
      }
    }
  }
  __syncthreads();                             // A reads done -> PS aliases A

  // ---------- publish split-K partials ----------
  {
    int crow0 = (lane>>4)*4;
    #pragma unroll
    for (int g=0;g<3;g++){
      float* slot = PSf + (size_t)(kq*12 + g*4 + cb)*PSTR;
      #pragma unroll
      for (int i=0;i<4;i++)
        slot[(crow0+i)*16 + l15] = acc[g][i];
    }
  }
  __syncthreads();

  // ---------- reduce + gates + rh ----------
  {
    int r = tid >> 6, f = tid & 63;
    int cb2 = f >> 4, c = f & 15;
    float az=0.f, ar=0.f, ah=0.f;
    #pragma unroll
    for (int k=0;k<4;k++){
      az += PSf[(size_t)(k*12 + 0 + cb2)*PSTR + r*16 + c];
      ar += PSf[(size_t)(k*12 + 4 + cb2)*PSTR + r*16 + c];
      ah += PSf[(size_t)(k*12 + 8 + cb2)*PSTR + r*16 + c];
    }
    float z  = 1.f/(1.f + expf(-(az + bz[f])));
    float rg = 1.f/(1.f + expf(-(ar + br[f])));
    float hv = hin[(size_t)(r0+r)*64 + f];
    zSf[tid] = z;
    rSf[tid] = rg;
    ushort hi,lo; split_bf(rg*hv,hi,lo);
    rhH[r*72+f] = hi;
    rhL[r*72+f] = lo;
    PSf[(size_t)(8 + cb2)*PSTR + r*16 + c] = ah;
  }
  __syncthreads();

  // ---------- waves 0..3: GEMM2 + blend + write ----------
  if (w < 4){
    const int colf = w*16 + l15;
    float4v acc2 = {0.f,0.f,0.f,0.f};
    #pragma unroll
    for (int kk=0; kk<2; ++kk){
      short8 aH = *(const short8*)&rhH[l15*72 + kk*32 + koff];
      short8 aL = *(const short8*)&rhL[l15*72 + kk*32 + koff];
      int boff = (((w<<1) + kk) << 9) + lane*8;
      short8 bH = *(const short8*)(PUH + boff);
      short8 bL = *(const short8*)(PUL + boff);
      acc2 = __builtin_amdgcn_mfma_f32_16x16x32_bf16(aH,bH,acc2,0,0,0);
      acc2 = __builtin_amdgcn_mfma_f32_16x16x32_bf16(aH,bL,acc2,0,0,0);
      acc2 = __builtin_amdgcn_mfma_f32_16x16x32_bf16(aL,bH,acc2,0,0,0);
    }
    const int crow0 = (lane>>4)*4;
    const float bhf = bh[colf];
    float* dst = last ? out : hout;
    #pragma unroll
    for (int i=0;i<4;i++){
      int row = crow0 + i;
      float ah = PSf[(size_t)(8 + w)*PSTR + row*16 + l15];
      float z  = zSf[row*64 + colf];
      float rg = rSf[row*64 + colf];
      float ht = tanhf(ah + acc2[i] + bhf);
      size_t idx = (size_t)(r0+row)*64 + colf;
      float hn = (1.f - z)*hin[idx] + rg*ht;
      dst[idx] = hn;
    }
  }
}

extern "C" void kernel_launch(void* const* d_in, const int* in_sizes, int n_in,
                              void* d_out, int out_size, void* d_ws, size_t ws_size,
                              hipStream_t stream) {
  const float* x    = (const float*)d_in[0];
  const float* edge = (const float*)d_in[1];
  const float* wz   = (const float*)d_in[2];
  const float* wr   = (const float*)d_in[3];
  const float* wh   = (const float*)d_in[4];
  const float* uz   = (const float*)d_in[5];
  const float* ur   = (const float*)d_in[6];
  const float* uh   = (const float*)d_in[7];
  const float* bz   = (const float*)d_in[8];
  const float* br   = (const float*)d_in[9];
  const float* bh   = (const float*)d_in[10];
  float* out = (float*)d_out;

  char* ws = (char*)d_ws;
  size_t off = 0;
  auto alloc = [&](size_t bytes)->void*{
    void* p = ws + off;
    off = (off + bytes + 255) & ~(size_t)255;
    return p;
  };
  const size_t EN = (size_t)NE * N_NOTES;            // 57344
  const size_t ND = (size_t)N_NOTES * SIZE;          // 262144
  int*    deg  = (int*)   alloc(EN * 4);
  ushort* adj  = (ushort*)alloc(EN * MAXDEG * 2);
  ushort* PWH  = (ushort*)alloc((size_t)PWN * 2);
  ushort* PWL  = (ushort*)alloc((size_t)PWN * 2);
  ushort* PUH  = (ushort*)alloc((size_t)PUN * 2);
  ushort* PUL  = (ushort*)alloc((size_t)PUN * 2);
  float*  h0   = (float*) alloc((size_t)HPAD * SIZE * 4);
  float*  h1   = (float*) alloc((size_t)HPAD * SIZE * 4);

  k_setup<<<2048, 256, 0, stream>>>(deg, (uint32_t*)adj,
                                    wz, wr, wh, uz, ur, uh,
                                    PWH, PWL, PUH, PUL,
                                    (const float4v*)x, (float4v*)h0,
                                    h0 + ND, h1 + ND);
  k_build<<<NE*N_NOTES, 256, 0, stream>>>((const float4v*)edge, deg, adj);

  float* hcur = h0;
  float* hnxt = h1;
  for (int it = 0; it < NITER; ++it){
    k_fused<<<N_NOTES/16, 1024, 0, stream>>>(deg, adj, PWH, PWL, PUH, PUL,
                                             bz, br, bh, hcur, hnxt,
                                             out, (it == NITER-1) ? 1 : 0);
    float* t = hcur; hcur = hnxt; hnxt = t;
  }
}